// Round 1
// baseline (102.185 us; speedup 1.0000x reference)
//
#include <hip/hip_runtime.h>
#include <math.h>

#define NB   4
#define SL   1024
#define NTOK (NB*SL)      // 4096
#define DM   64           // d_model
#define DI   128          // d_inner
#define DSt  128          // d_state
#define SEGLEN 64
#define NSEG (SL/SEGLEN)  // 16

// ---- workspace layout (float offsets) ----
#define OFF_GATE   0
#define OFF_DELTA  (OFF_GATE  + NTOK*DI)   // softplus(delta) raw
#define OFF_BM     (OFF_DELTA + NTOK*DI)   // Bm + bias
#define OFF_CM     (OFF_BM    + NTOK*DSt)  // Cm + bias
#define OFF_XPOOL  (OFF_CM    + NTOK*DSt)  // x_pool per token
#define OFF_WPOOL  (OFF_XPOOL + NTOK)      // 64 floats
#define OFF_W4     (OFF_WPOOL + 64)        // W_out repacked for coalesced reads (2048 float4)
#define OFF_ABAR   (OFF_W4    + DM*DI)
#define OFF_HEND   (OFF_ABAR  + NTOK*DSt)  // per-segment local final h
#define OFF_P      (OFF_HEND  + NB*NSEG*DSt) // per-segment prod(a)
#define OFF_Y      (OFF_P     + NB*NSEG*DSt) // scan output y[b,t]

static __device__ __forceinline__ float wave64_sum(float v) {
#pragma unroll
    for (int m = 32; m >= 1; m >>= 1) v += __shfl_xor(v, m, 64);
    return v;
}

// ---- K0: prep — w_pool (mean of first 128 W_in rows) + W_out repack ----
__global__ __launch_bounds__(256) void k_prep(const float* __restrict__ W_in,
                                              const float* __restrict__ W_out,
                                              float* __restrict__ ws) {
    const int tid = threadIdx.x;
    if (tid < DM) {
        float acc = 0.f;
#pragma unroll 8
        for (int i = 0; i < DI; ++i) acc += W_in[i*DM + tid];
        ws[OFF_WPOOL + tid] = acc * (1.0f/DI);
    }
    // W4[q*64+d] = float4(W_out[d][4q..4q+3]) -> lane-d coalesced dwordx4 in k_out
    float4* W4 = (float4*)(ws + OFF_W4);
    for (int k = tid; k < 32*64; k += 256) {
        const int d = k & 63, q = k >> 6;
        W4[k] = *(const float4*)(W_out + d*DI + q*4);
    }
}

// ---- K1: projections. grid = 16 token-groups x 16 dim-groups; thread <-> token ----
__global__ __launch_bounds__(256) void k_proj(
    const float* __restrict__ x, const float* __restrict__ W_in,
    const float* __restrict__ W_delta, const float* __restrict__ b_delta,
    const float* __restrict__ W_B, const float* __restrict__ b_B,
    const float* __restrict__ W_C, const float* __restrict__ b_C,
    float* __restrict__ ws)
{
    const int tid = threadIdx.x;
    const int tg  = blockIdx.x >> 4;
    const int g   = blockIdx.x & 15;
    const int tok = tg*256 + tid;

    float4 xr[16];
    const float4* xp4 = (const float4*)(x + tok*DM);
#pragma unroll
    for (int k = 0; k < 16; ++k) xr[k] = xp4[k];

    const int cat = g >> 2;          // 0 gate, 1 delta, 2 B, 3 C
    const int r0  = (g & 3) * 32;
    const float* Wbase; const float* bias; float* dst;
    if      (cat == 0) { Wbase = W_in + DI*DM; bias = nullptr; dst = ws + OFF_GATE;  }
    else if (cat == 1) { Wbase = W_delta;      bias = b_delta; dst = ws + OFF_DELTA; }
    else if (cat == 2) { Wbase = W_B;          bias = b_B;     dst = ws + OFF_BM;    }
    else               { Wbase = W_C;          bias = b_C;     dst = ws + OFF_CM;    }

#pragma unroll 2
    for (int e = 0; e < 32; ++e) {
        const int row = r0 + e;
        const float* w = Wbase + row*DM;   // block-uniform -> scalar loads
        float a0 = 0.f, a1 = 0.f, a2 = 0.f, a3 = 0.f;
#pragma unroll
        for (int k = 0; k < 16; ++k) {
            const float4 wv = *(const float4*)(w + 4*k);
            a0 = fmaf(wv.x, xr[k].x, a0);
            a1 = fmaf(wv.y, xr[k].y, a1);
            a2 = fmaf(wv.z, xr[k].z, a2);
            a3 = fmaf(wv.w, xr[k].w, a3);
        }
        float acc = (a0+a1) + (a2+a3);
        if (bias) acc += bias[row];
        if (cat == 1)  // softplus, numerically stable
            acc = fmaxf(acc, 0.f) + log1pf(expf(-fabsf(acc)));
        dst[tok*128 + row] = acc;
    }
    if (g == 0) {  // x_pool via w_pool (linearity of mean over x_ssm dims)
        const float* wp = ws + OFF_WPOOL;
        float a0 = 0.f, a1 = 0.f, a2 = 0.f, a3 = 0.f;
#pragma unroll
        for (int k = 0; k < 16; ++k) {
            const float4 wv = *(const float4*)(wp + 4*k);
            a0 = fmaf(wv.x, xr[k].x, a0);
            a1 = fmaf(wv.y, xr[k].y, a1);
            a2 = fmaf(wv.z, xr[k].z, a2);
            a3 = fmaf(wv.w, xr[k].w, a3);
        }
        ws[OFF_XPOOL + tok] = (a0+a1) + (a2+a3);
    }
}

// ---- K2: Abar[b,l,s] = mean_i exp(delta_i * A[i,s]); A staged in LDS ----
__global__ __launch_bounds__(256) void k_abar(const float* __restrict__ A,
                                              float* __restrict__ ws)
{
    __shared__ float Al[DI*DSt];   // 64 KB
    const int tid = threadIdx.x;
    const float4* A4 = (const float4*)A;
    float4* Al4 = (float4*)Al;
#pragma unroll
    for (int k = 0; k < 16; ++k) Al4[k*256 + tid] = A4[k*256 + tid];
    __syncthreads();

    const float* delta = ws + OFF_DELTA;
    float*       Abar  = ws + OFF_ABAR;
    const int s    = tid & 127;
    const int half = tid >> 7;          // two tokens concurrently
    const int base = blockIdx.x * 16;
    for (int p = 0; p < 8; ++p) {
        const int tok = base + p*2 + half;
        const float* dv = delta + tok*DI;
        float a0 = 0.f, a1 = 0.f, a2 = 0.f, a3 = 0.f;
#pragma unroll 2
        for (int i = 0; i < DI; i += 4) {
            a0 += __expf(dv[i]   * Al[(i  )*DSt + s]);
            a1 += __expf(dv[i+1] * Al[(i+1)*DSt + s]);
            a2 += __expf(dv[i+2] * Al[(i+2)*DSt + s]);
            a3 += __expf(dv[i+3] * Al[(i+3)*DSt + s]);
        }
        Abar[tok*DSt + s] = ((a0+a1) + (a2+a3)) * (1.0f/DI);
    }
}

// ---- K3: scan pass 1 — per-segment local scan (h0=0), record h_end & prod(a) ----
__global__ __launch_bounds__(128) void k_scan1(float* __restrict__ ws)
{
    const int s   = threadIdx.x;
    const int b   = blockIdx.x >> 4;
    const int seg = blockIdx.x & 15;
    const float* Abar  = ws + OFF_ABAR;
    const float* Bm    = ws + OFF_BM;
    const float* xpool = ws + OFF_XPOOL;
    float h = 0.f, p = 1.f;
    const int t0 = b*SL + seg*SEGLEN;
#pragma unroll 8
    for (int t = 0; t < SEGLEN; ++t) {
        const float a  = Abar[(t0 + t)*DSt + s];
        const float bx = Bm[(t0 + t)*DSt + s] * xpool[t0 + t];
        h = fmaf(a, h, bx);
        p *= a;
    }
    ws[OFF_HEND + blockIdx.x*DSt + s] = h;
    ws[OFF_P    + blockIdx.x*DSt + s] = p;
}

// ---- K4: scan pass 2 — redundant prefix stitch, re-scan with y = c.h ----
__global__ __launch_bounds__(128) void k_scan2(float* __restrict__ ws)
{
    __shared__ float prod[SEGLEN][133];  // pad 133: 2-way (free) bank access
    __shared__ float psum[2][64];
    const int s   = threadIdx.x;
    const int b   = blockIdx.x >> 4;
    const int seg = blockIdx.x & 15;
    const float* Abar  = ws + OFF_ABAR;
    const float* Bm    = ws + OFF_BM;
    const float* Cm    = ws + OFF_CM;
    const float* xpool = ws + OFF_XPOOL;
    const float* hend  = ws + OFF_HEND;
    const float* P     = ws + OFF_P;

    float h = 0.f;
    for (int j = 0; j < seg; ++j) {      // <=15 iters, block-uniform
        const int idx = (b*NSEG + j)*DSt + s;
        h = fmaf(P[idx], h, hend[idx]);
    }
    const int t0 = b*SL + seg*SEGLEN;
#pragma unroll 4
    for (int t = 0; t < SEGLEN; ++t) {
        const float a  = Abar[(t0 + t)*DSt + s];
        const float bx = Bm[(t0 + t)*DSt + s] * xpool[t0 + t];
        h = fmaf(a, h, bx);
        prod[t][s] = Cm[(t0 + t)*DSt + s] * h;
    }
    __syncthreads();
    const int r = s & 63, hh = s >> 6;
    float acc = 0.f;
#pragma unroll
    for (int k = 0; k < 64; ++k) acc += prod[r][hh*64 + k];
    psum[hh][r] = acc;
    __syncthreads();
    if (s < 64)
        ws[OFF_Y + b*SL + seg*SEGLEN + s] = psum[0][s] + psum[1][s];
}

// ---- K5: y*silu(gate) @ W_out^T + residual + LayerNorm (wave per token) ----
__global__ __launch_bounds__(256) void k_out(
    const float* __restrict__ x, const float* __restrict__ ln_w,
    const float* __restrict__ ln_b, const float* __restrict__ ws,
    float* __restrict__ out)
{
    __shared__ float vbuf[4][128];
    const int tid = threadIdx.x;
    const int d   = tid & 63;
    const int wv  = tid >> 6;
    const float* gate = ws + OFF_GATE;
    const float4* W4  = (const float4*)(ws + OFF_W4);
    const float* y    = ws + OFF_Y;
    const float lw = ln_w[d], lb = ln_b[d];

    for (int j = 0; j < 4; ++j) {
        const int tok = blockIdx.x*16 + j*4 + wv;
        const float yt = y[tok];
        const float g0 = gate[tok*DI + d];
        const float g1 = gate[tok*DI + 64 + d];
        const float v0 = yt * (g0 / (1.f + __expf(-g0)));
        const float v1 = yt * (g1 / (1.f + __expf(-g1)));
        __syncthreads();               // protect vbuf across j iterations
        vbuf[wv][d]      = v0;
        vbuf[wv][64 + d] = v1;
        __syncthreads();
        float ac0 = 0.f, ac1 = 0.f, ac2 = 0.f, ac3 = 0.f;
#pragma unroll 8
        for (int q = 0; q < 32; ++q) {
            const float4 w  = W4[q*64 + d];                     // coalesced
            const float4 vv = *(const float4*)&vbuf[wv][q*4];   // broadcast
            ac0 = fmaf(w.x, vv.x, ac0);
            ac1 = fmaf(w.y, vv.y, ac1);
            ac2 = fmaf(w.z, vv.z, ac2);
            ac3 = fmaf(w.w, vv.w, ac3);
        }
        const float z  = (ac0+ac1) + (ac2+ac3) + x[tok*DM + d];
        const float s1 = wave64_sum(z);
        const float s2 = wave64_sum(z*z);
        const float mu  = s1 * (1.f/64.f);
        const float var = s2 * (1.f/64.f) - mu*mu;
        out[tok*DM + d] = (z - mu) * rsqrtf(var + 1e-5f) * lw + lb;
    }
}

extern "C" void kernel_launch(void* const* d_in, const int* in_sizes, int n_in,
                              void* d_out, int out_size, void* d_ws, size_t ws_size,
                              hipStream_t stream) {
    const float* x       = (const float*)d_in[0];
    const float* W_in    = (const float*)d_in[1];
    const float* W_delta = (const float*)d_in[2];
    const float* b_delta = (const float*)d_in[3];
    const float* W_B     = (const float*)d_in[4];
    const float* b_B     = (const float*)d_in[5];
    const float* W_C     = (const float*)d_in[6];
    const float* b_C     = (const float*)d_in[7];
    const float* A       = (const float*)d_in[8];
    const float* W_out   = (const float*)d_in[9];
    const float* ln_w    = (const float*)d_in[10];
    const float* ln_b    = (const float*)d_in[11];
    float* out = (float*)d_out;
    float* ws  = (float*)d_ws;

    hipLaunchKernelGGL(k_prep,  dim3(1),   dim3(256), 0, stream, W_in, W_out, ws);
    hipLaunchKernelGGL(k_proj,  dim3(256), dim3(256), 0, stream,
                       x, W_in, W_delta, b_delta, W_B, b_B, W_C, b_C, ws);
    hipLaunchKernelGGL(k_abar,  dim3(256), dim3(256), 0, stream, A, ws);
    hipLaunchKernelGGL(k_scan1, dim3(64),  dim3(128), 0, stream, ws);
    hipLaunchKernelGGL(k_scan2, dim3(64),  dim3(128), 0, stream, ws);
    hipLaunchKernelGGL(k_out,   dim3(256), dim3(256), 0, stream, x, ln_w, ln_b, ws, out);
}

// Round 2
// 71.695 us; speedup vs baseline: 1.4253x; 1.4253x over previous
//
#include <hip/hip_runtime.h>
#include <math.h>

#define NB   4
#define SL   1024
#define NTOK (NB*SL)      // 4096
#define DM   64           // d_model
#define DI   128          // d_inner
#define DSt  128          // d_state
#define SEGLEN 16
#define NSEG (SL/SEGLEN)  // 64

// ---- workspace layout (float offsets) ----
#define OFF_GATE   0
#define OFF_DELTA  (OFF_GATE  + NTOK*DI)     // softplus(delta); dead after k_abar
#define OFF_BM     (OFF_DELTA + NTOK*DI)
#define OFF_CM     (OFF_BM    + NTOK*DSt)
#define OFF_XPOOL  (OFF_CM    + NTOK*DSt)
#define OFF_ABAR   (OFF_XPOOL + NTOK)
#define OFF_Y      (OFF_ABAR  + NTOK*DSt)
// aliases into the dead DELTA region (written by k_scan1, after k_abar is done)
#define OFF_HEND   (OFF_DELTA)                       // NB*NSEG*DSt = 32768
#define OFF_P      (OFF_DELTA + NB*NSEG*DSt)         // 32768

static __device__ __forceinline__ float wave64_sum(float v) {
#pragma unroll
    for (int m = 32; m >= 1; m >>= 1) v += __shfl_xor(v, m, 64);
    return v;
}

// ---- K1: projections. grid = 16 token-groups x 64 row-groups (8 rows) ----
__global__ __launch_bounds__(256) void k_proj(
    const float* __restrict__ x, const float* __restrict__ W_in,
    const float* __restrict__ W_delta, const float* __restrict__ b_delta,
    const float* __restrict__ W_B, const float* __restrict__ b_B,
    const float* __restrict__ W_C, const float* __restrict__ b_C,
    float* __restrict__ ws)
{
    __shared__ float wp[DM];
    const int tid = threadIdx.x;
    const int tg  = blockIdx.x >> 6;          // token group (256 tokens)
    const int g   = blockIdx.x & 63;          // row group (8 rows)
    const int tok = tg*256 + tid;

    float4 xr[16];
    const float4* xp4 = (const float4*)(x + tok*DM);
#pragma unroll
    for (int k = 0; k < 16; ++k) xr[k] = xp4[k];

    const int cat = g >> 4;                   // 0 gate, 1 delta, 2 B, 3 C
    const int r0  = (g & 15) * 8;
    const float* Wbase; const float* bias; float* dst;
    if      (cat == 0) { Wbase = W_in + DI*DM; bias = nullptr; dst = ws + OFF_GATE;  }
    else if (cat == 1) { Wbase = W_delta;      bias = b_delta; dst = ws + OFF_DELTA; }
    else if (cat == 2) { Wbase = W_B;          bias = b_B;     dst = ws + OFF_BM;    }
    else               { Wbase = W_C;          bias = b_C;     dst = ws + OFF_CM;    }

#pragma unroll 2
    for (int e = 0; e < 8; ++e) {
        const int row = r0 + e;
        const float* w = Wbase + row*DM;      // block-uniform -> scalar loads
        float a0 = 0.f, a1 = 0.f, a2 = 0.f, a3 = 0.f;
#pragma unroll
        for (int k = 0; k < 16; ++k) {
            const float4 wv = *(const float4*)(w + 4*k);
            a0 = fmaf(wv.x, xr[k].x, a0);
            a1 = fmaf(wv.y, xr[k].y, a1);
            a2 = fmaf(wv.z, xr[k].z, a2);
            a3 = fmaf(wv.w, xr[k].w, a3);
        }
        float acc = (a0+a1) + (a2+a3);
        if (bias) acc += bias[row];
        if (cat == 1)  // softplus, numerically stable
            acc = fmaxf(acc, 0.f) + log1pf(__expf(-fabsf(acc)));
        dst[tok*128 + row] = acc;
    }

    if (g == 0) {  // x_pool = x . w_pool  (linearity of mean over x_ssm dims)
        if (tid < DM) {
            float acc = 0.f;
#pragma unroll 8
            for (int i = 0; i < DI; ++i) acc += W_in[i*DM + tid];  // coalesced
            wp[tid] = acc * (1.0f/DI);
        }
        __syncthreads();
        float a0 = 0.f, a1 = 0.f, a2 = 0.f, a3 = 0.f;
#pragma unroll
        for (int k = 0; k < 16; ++k) {
            const float4 wv = *(const float4*)(wp + 4*k);   // uniform broadcast
            a0 = fmaf(wv.x, xr[k].x, a0);
            a1 = fmaf(wv.y, xr[k].y, a1);
            a2 = fmaf(wv.z, xr[k].z, a2);
            a3 = fmaf(wv.w, xr[k].w, a3);
        }
        ws[OFF_XPOOL + tok] = (a0+a1) + (a2+a3);
    }
}

// ---- K2: Abar[t,s] = mean_i exp(delta[t,i] * A[i,s]); A column in VGPRs ----
__global__ __launch_bounds__(256, 2) void k_abar(const float* __restrict__ A,
                                                 float* __restrict__ ws)
{
    const int tid  = threadIdx.x;
    const int s    = tid & 127;
    const int half = tid >> 7;
    float areg[DI];
#pragma unroll
    for (int i = 0; i < DI; ++i) areg[i] = A[i*DSt + s];   // coalesced, L2-hot

    const float* delta = ws + OFF_DELTA;
    float*       Abar  = ws + OFF_ABAR;
    const int base = blockIdx.x * 8 + half * 4;
#pragma unroll
    for (int p = 0; p < 4; ++p) {
        const int tok = base + p;
        const float* dv = delta + tok*DI;
        float a0 = 0.f, a1 = 0.f, a2 = 0.f, a3 = 0.f;
#pragma unroll
        for (int i4 = 0; i4 < DI/4; ++i4) {
            const float4 d4 = *(const float4*)(dv + 4*i4);  // wave-uniform bcast
            a0 += __expf(d4.x * areg[4*i4    ]);
            a1 += __expf(d4.y * areg[4*i4 + 1]);
            a2 += __expf(d4.z * areg[4*i4 + 2]);
            a3 += __expf(d4.w * areg[4*i4 + 3]);
        }
        Abar[tok*DSt + s] = ((a0+a1) + (a2+a3)) * (1.0f/DI);
    }
}

// ---- K3: scan pass 1 — per-segment local scan (h0=0) ----
__global__ __launch_bounds__(128) void k_scan1(float* __restrict__ ws)
{
    const int s   = threadIdx.x;
    const int b   = blockIdx.x >> 6;
    const int seg = blockIdx.x & 63;
    const float* Abar  = ws + OFF_ABAR;
    const float* Bm    = ws + OFF_BM;
    const float* xpool = ws + OFF_XPOOL;
    float h = 0.f, p = 1.f;
    const int t0 = b*SL + seg*SEGLEN;
#pragma unroll
    for (int t = 0; t < SEGLEN; ++t) {
        const float a  = Abar[(t0 + t)*DSt + s];
        const float bx = Bm[(t0 + t)*DSt + s] * xpool[t0 + t];
        h = fmaf(a, h, bx);
        p *= a;
    }
    ws[OFF_HEND + blockIdx.x*DSt + s] = h;
    ws[OFF_P    + blockIdx.x*DSt + s] = p;
}

// ---- K4: scan pass 2 — redundant prefix stitch + y = c.h reduce ----
__global__ __launch_bounds__(128) void k_scan2(float* __restrict__ ws)
{
    __shared__ float prod[SEGLEN][132];   // pad 132: 16B-aligned, spread banks
    const int s   = threadIdx.x;
    const int b   = blockIdx.x >> 6;
    const int seg = blockIdx.x & 63;
    const float* Abar  = ws + OFF_ABAR;
    const float* Bm    = ws + OFF_BM;
    const float* Cm    = ws + OFF_CM;
    const float* xpool = ws + OFF_XPOOL;
    const float* hend  = ws + OFF_HEND;
    const float* P     = ws + OFF_P;

    float h = 0.f;
#pragma unroll 4
    for (int j = 0; j < seg; ++j) {       // block-uniform count, coalesced loads
        const int idx = (b*NSEG + j)*DSt + s;
        h = fmaf(P[idx], h, hend[idx]);
    }
    const int t0 = b*SL + seg*SEGLEN;
#pragma unroll
    for (int t = 0; t < SEGLEN; ++t) {
        const float a  = Abar[(t0 + t)*DSt + s];
        const float bx = Bm[(t0 + t)*DSt + s] * xpool[t0 + t];
        h = fmaf(a, h, bx);
        prod[t][s] = Cm[(t0 + t)*DSt + s] * h;
    }
    __syncthreads();
    const int t = s >> 3, r = s & 7;      // 16 tokens x 8 lanes
    float4 acc4 = {0.f,0.f,0.f,0.f};
#pragma unroll
    for (int k4 = 0; k4 < 4; ++k4) {
        const float4 v = *(const float4*)(&prod[t][r*16 + 4*k4]);
        acc4.x += v.x; acc4.y += v.y; acc4.z += v.z; acc4.w += v.w;
    }
    float acc = (acc4.x + acc4.y) + (acc4.z + acc4.w);
#pragma unroll
    for (int m = 1; m <= 4; m <<= 1) acc += __shfl_xor(acc, m, 64);
    if (r == 0) ws[OFF_Y + b*SL + seg*SEGLEN + t] = acc;
}

// ---- K5: y*silu(gate) @ W_out^T + residual + LayerNorm; wave per token ----
__global__ __launch_bounds__(256) void k_out(
    const float* __restrict__ x, const float* __restrict__ W_out,
    const float* __restrict__ ln_w, const float* __restrict__ ln_b,
    const float* __restrict__ ws, float* __restrict__ out)
{
    __shared__ float Wl[DM*132];          // [64][132] padded
    __shared__ float vbuf[4][DI];
    const int tid = threadIdx.x;
    const int d   = tid & 63;
    const int wv  = tid >> 6;
    const int tok = blockIdx.x*4 + wv;

    const float4* W4g = (const float4*)W_out;
#pragma unroll
    for (int j = 0; j < 8; ++j) {         // stage W_out coalesced -> padded LDS
        const int f = tid + j*256;        // float4 index, 2048 total
        const int row = f >> 5, c4 = f & 31;
        *(float4*)(&Wl[row*132 + c4*4]) = W4g[f];
    }

    const float* gate = ws + OFF_GATE;
    const float* y    = ws + OFF_Y;
    const float yt = y[tok];
    const float g0 = gate[tok*DI + d];
    const float g1 = gate[tok*DI + 64 + d];
    vbuf[wv][d]      = yt * (g0 / (1.f + __expf(-g0)));
    vbuf[wv][64 + d] = yt * (g1 / (1.f + __expf(-g1)));
    __syncthreads();

    float ac0 = 0.f, ac1 = 0.f, ac2 = 0.f, ac3 = 0.f;
#pragma unroll 8
    for (int q = 0; q < 32; ++q) {
        const float4 w  = *(const float4*)(&Wl[d*132 + q*4]);   // conflict-free
        const float4 vv = *(const float4*)(&vbuf[wv][q*4]);     // broadcast
        ac0 = fmaf(w.x, vv.x, ac0);
        ac1 = fmaf(w.y, vv.y, ac1);
        ac2 = fmaf(w.z, vv.z, ac2);
        ac3 = fmaf(w.w, vv.w, ac3);
    }
    const float z  = (ac0+ac1) + (ac2+ac3) + x[tok*DM + d];
    const float s1 = wave64_sum(z);
    const float s2 = wave64_sum(z*z);
    const float mu  = s1 * (1.f/64.f);
    const float var = s2 * (1.f/64.f) - mu*mu;
    out[tok*DM + d] = (z - mu) * rsqrtf(var + 1e-5f) * ln_w[d] + ln_b[d];
}

extern "C" void kernel_launch(void* const* d_in, const int* in_sizes, int n_in,
                              void* d_out, int out_size, void* d_ws, size_t ws_size,
                              hipStream_t stream) {
    const float* x       = (const float*)d_in[0];
    const float* W_in    = (const float*)d_in[1];
    const float* W_delta = (const float*)d_in[2];
    const float* b_delta = (const float*)d_in[3];
    const float* W_B     = (const float*)d_in[4];
    const float* b_B     = (const float*)d_in[5];
    const float* W_C     = (const float*)d_in[6];
    const float* b_C     = (const float*)d_in[7];
    const float* A       = (const float*)d_in[8];
    const float* W_out   = (const float*)d_in[9];
    const float* ln_w    = (const float*)d_in[10];
    const float* ln_b    = (const float*)d_in[11];
    float* out = (float*)d_out;
    float* ws  = (float*)d_ws;

    hipLaunchKernelGGL(k_proj,  dim3(1024), dim3(256), 0, stream,
                       x, W_in, W_delta, b_delta, W_B, b_B, W_C, b_C, ws);
    hipLaunchKernelGGL(k_abar,  dim3(512),  dim3(256), 0, stream, A, ws);
    hipLaunchKernelGGL(k_scan1, dim3(256),  dim3(128), 0, stream, ws);
    hipLaunchKernelGGL(k_scan2, dim3(256),  dim3(128), 0, stream, ws);
    hipLaunchKernelGGL(k_out,   dim3(1024), dim3(256), 0, stream,
                       x, W_out, ln_w, ln_b, ws, out);
}

// Round 3
// 54.550 us; speedup vs baseline: 1.8733x; 1.3143x over previous
//
#include <hip/hip_runtime.h>
#include <math.h>

#define NB   4
#define SL   1024
#define NTOK (NB*SL)      // 4096
#define DM   64           // d_model
#define DI   128          // d_inner
#define DSt  128          // d_state
#define SEGLEN 16
#define NSEG (SL/SEGLEN)  // 64

// ---- workspace layout (float offsets) ----
#define OFF_GATE   0
#define OFF_DELTA  (OFF_GATE  + NTOK*DI)     // softplus(delta); dead after k_abar
#define OFF_BM     (OFF_DELTA + NTOK*DI)
#define OFF_CM     (OFF_BM    + NTOK*DSt)
#define OFF_XPOOL  (OFF_CM    + NTOK*DSt)
#define OFF_ABAR   (OFF_XPOOL + NTOK)
#define OFF_Y      (OFF_ABAR  + NTOK*DSt)
// aliases into the dead DELTA region (written by k_scan1, after k_abar is done)
#define OFF_HEND   (OFF_DELTA)                       // NB*NSEG*DSt = 32768
#define OFF_P      (OFF_DELTA + NB*NSEG*DSt)         // 32768

#define PROJ_TG   128
#define PROJ_TOK  (NTOK/PROJ_TG)   // 32 tokens per block

static __device__ __forceinline__ float wave64_sum(float v) {
#pragma unroll
    for (int m = 32; m >= 1; m >>= 1) v += __shfl_xor(v, m, 64);
    return v;
}

// ---- K1: projections, row-per-lane layout.
// grid = 4 cats x 128 token-groups. Lane l owns output rows l and l+64 (weights
// in VGPRs); x tile staged coalesced in LDS, read as wave-uniform broadcast;
// stores coalesced (lane = consecutive row).
__global__ __launch_bounds__(256) void k_proj(
    const float* __restrict__ x, const float* __restrict__ W_in,
    const float* __restrict__ W_delta, const float* __restrict__ b_delta,
    const float* __restrict__ W_B, const float* __restrict__ b_B,
    const float* __restrict__ W_C, const float* __restrict__ b_C,
    float* __restrict__ ws)
{
    __shared__ float xl[PROJ_TOK*DM];   // 8 KB
    const int tid = threadIdx.x;
    const int l   = tid & 63;
    const int w   = tid >> 6;
    const int cat = blockIdx.x >> 7;    // 0 gate, 1 delta, 2 B, 3 C
    const int tg  = blockIdx.x & (PROJ_TG-1);
    const int tok0 = tg * PROJ_TOK;

    // stage x tile (coalesced): 512 float4 over 256 threads
    {
        const float4* xg = (const float4*)(x + tok0*DM);
        float4* xl4 = (float4*)xl;
        xl4[tid]       = xg[tid];
        xl4[tid + 256] = xg[tid + 256];
    }
    __syncthreads();

    const float* Wbase; const float* bias; float* dst;
    if      (cat == 0) { Wbase = W_in + DI*DM; bias = nullptr; dst = ws + OFF_GATE;  }
    else if (cat == 1) { Wbase = W_delta;      bias = b_delta; dst = ws + OFF_DELTA; }
    else if (cat == 2) { Wbase = W_B;          bias = b_B;     dst = ws + OFF_BM;    }
    else               { Wbase = W_C;          bias = b_C;     dst = ws + OFF_CM;    }

    // per-lane weight rows l and l+64 -> VGPRs (one-time, L2-hot)
    float4 w0[16], w1[16];
    {
        const float4* Wr0 = (const float4*)(Wbase + l*DM);
        const float4* Wr1 = (const float4*)(Wbase + (l+64)*DM);
#pragma unroll
        for (int k = 0; k < 16; ++k) { w0[k] = Wr0[k]; w1[k] = Wr1[k]; }
    }
    float bias0 = 0.f, bias1 = 0.f;
    if (bias) { bias0 = bias[l]; bias1 = bias[l+64]; }

#pragma unroll 2
    for (int it = 0; it < PROJ_TOK/4; ++it) {
        const int tl = it*4 + w;        // wave-uniform local token
        float a0=0.f,a1=0.f,a2=0.f,a3=0.f, c0=0.f,c1=0.f,c2=0.f,c3=0.f;
#pragma unroll
        for (int k = 0; k < 16; ++k) {
            const float4 xv = *(const float4*)(xl + tl*DM + 4*k);  // broadcast
            a0 = fmaf(w0[k].x, xv.x, a0);
            a1 = fmaf(w0[k].y, xv.y, a1);
            a2 = fmaf(w0[k].z, xv.z, a2);
            a3 = fmaf(w0[k].w, xv.w, a3);
            c0 = fmaf(w1[k].x, xv.x, c0);
            c1 = fmaf(w1[k].y, xv.y, c1);
            c2 = fmaf(w1[k].z, xv.z, c2);
            c3 = fmaf(w1[k].w, xv.w, c3);
        }
        float ra = (a0+a1) + (a2+a3) + bias0;
        float rb = (c0+c1) + (c2+c3) + bias1;
        if (cat == 1) {  // softplus, numerically stable
            ra = fmaxf(ra, 0.f) + log1pf(__expf(-fabsf(ra)));
            rb = fmaxf(rb, 0.f) + log1pf(__expf(-fabsf(rb)));
        }
        const int tok = tok0 + tl;
        dst[tok*128 + l]      = ra;   // coalesced 256B
        dst[tok*128 + 64 + l] = rb;   // coalesced 256B
    }

    if (cat == 0) {   // x_pool = x . w_pool (fold mean over x_ssm dims into weights)
        float wp = 0.f;
#pragma unroll 8
        for (int i = 0; i < DI; ++i) wp += W_in[i*DM + l];   // coalesced
        wp *= (1.0f/DI);
#pragma unroll
        for (int it = 0; it < PROJ_TOK/4; ++it) {
            const int tl = it*4 + w;
            float v = xl[tl*DM + l] * wp;   // stride-1: conflict-free
            v = wave64_sum(v);
            if (l == 0) ws[OFF_XPOOL + tok0 + tl] = v;
        }
    }
}

// ---- K2: Abar[t,s] = mean_i exp(delta[t,i] * A[i,s]); A column in VGPRs ----
__global__ __launch_bounds__(256, 2) void k_abar(const float* __restrict__ A,
                                                 float* __restrict__ ws)
{
    const int tid  = threadIdx.x;
    const int s    = tid & 127;
    const int half = tid >> 7;
    float areg[DI];
#pragma unroll
    for (int i = 0; i < DI; ++i) areg[i] = A[i*DSt + s];   // coalesced, L2-hot

    const float* delta = ws + OFF_DELTA;
    float*       Abar  = ws + OFF_ABAR;
    const int base = blockIdx.x * 8 + half * 4;
#pragma unroll
    for (int p = 0; p < 4; ++p) {
        const int tok = base + p;
        const float* dv = delta + tok*DI;
        float a0 = 0.f, a1 = 0.f, a2 = 0.f, a3 = 0.f;
#pragma unroll
        for (int i4 = 0; i4 < DI/4; ++i4) {
            const float4 d4 = *(const float4*)(dv + 4*i4);  // wave-uniform bcast
            a0 += __expf(d4.x * areg[4*i4    ]);
            a1 += __expf(d4.y * areg[4*i4 + 1]);
            a2 += __expf(d4.z * areg[4*i4 + 2]);
            a3 += __expf(d4.w * areg[4*i4 + 3]);
        }
        Abar[tok*DSt + s] = ((a0+a1) + (a2+a3)) * (1.0f/DI);
    }
}

// ---- K3: scan pass 1 — per-segment local scan (h0=0) ----
__global__ __launch_bounds__(128) void k_scan1(float* __restrict__ ws)
{
    const int s   = threadIdx.x;
    const int b   = blockIdx.x >> 6;
    const int seg = blockIdx.x & 63;
    const float* Abar  = ws + OFF_ABAR;
    const float* Bm    = ws + OFF_BM;
    const float* xpool = ws + OFF_XPOOL;
    float h = 0.f, p = 1.f;
    const int t0 = b*SL + seg*SEGLEN;
#pragma unroll
    for (int t = 0; t < SEGLEN; ++t) {
        const float a  = Abar[(t0 + t)*DSt + s];
        const float bx = Bm[(t0 + t)*DSt + s] * xpool[t0 + t];
        h = fmaf(a, h, bx);
        p *= a;
    }
    ws[OFF_HEND + blockIdx.x*DSt + s] = h;
    ws[OFF_P    + blockIdx.x*DSt + s] = p;
}

// ---- K4: scan pass 2 — redundant prefix stitch + y = c.h reduce ----
__global__ __launch_bounds__(128) void k_scan2(float* __restrict__ ws)
{
    __shared__ float prod[SEGLEN][132];
    const int s   = threadIdx.x;
    const int b   = blockIdx.x >> 6;
    const int seg = blockIdx.x & 63;
    const float* Abar  = ws + OFF_ABAR;
    const float* Bm    = ws + OFF_BM;
    const float* Cm    = ws + OFF_CM;
    const float* xpool = ws + OFF_XPOOL;
    const float* hend  = ws + OFF_HEND;
    const float* P     = ws + OFF_P;

    float h = 0.f;
#pragma unroll 4
    for (int j = 0; j < seg; ++j) {       // block-uniform count, coalesced loads
        const int idx = (b*NSEG + j)*DSt + s;
        h = fmaf(P[idx], h, hend[idx]);
    }
    const int t0 = b*SL + seg*SEGLEN;
#pragma unroll
    for (int t = 0; t < SEGLEN; ++t) {
        const float a  = Abar[(t0 + t)*DSt + s];
        const float bx = Bm[(t0 + t)*DSt + s] * xpool[t0 + t];
        h = fmaf(a, h, bx);
        prod[t][s] = Cm[(t0 + t)*DSt + s] * h;
    }
    __syncthreads();
    const int t = s >> 3, r = s & 7;      // 16 tokens x 8 lanes
    float4 acc4 = {0.f,0.f,0.f,0.f};
#pragma unroll
    for (int k4 = 0; k4 < 4; ++k4) {
        const float4 v = *(const float4*)(&prod[t][r*16 + 4*k4]);
        acc4.x += v.x; acc4.y += v.y; acc4.z += v.z; acc4.w += v.w;
    }
    float acc = (acc4.x + acc4.y) + (acc4.z + acc4.w);
#pragma unroll
    for (int m = 1; m <= 4; m <<= 1) acc += __shfl_xor(acc, m, 64);
    if (r == 0) ws[OFF_Y + b*SL + seg*SEGLEN + t] = acc;
}

// ---- K5: y*silu(gate) @ W_out^T + residual + LayerNorm; wave per token,
//      16 tokens per block to amortize W_out staging; XOR-swizzled LDS ----
__global__ __launch_bounds__(256) void k_out(
    const float* __restrict__ x, const float* __restrict__ W_out,
    const float* __restrict__ ln_w, const float* __restrict__ ln_b,
    const float* __restrict__ ws, float* __restrict__ out)
{
    __shared__ float4 Wl[DM*32];          // [row][col^ (row&7)] swizzled
    __shared__ float vbuf[4][DI];
    const int tid = threadIdx.x;
    const int d   = tid & 63;
    const int wv  = tid >> 6;

    const float4* W4g = (const float4*)W_out;
#pragma unroll
    for (int j = 0; j < 8; ++j) {         // stage W_out coalesced -> swizzled LDS
        const int f = tid + j*256;        // float4 index, 2048 total
        const int row = f >> 5, c4 = f & 31;
        Wl[row*32 + (c4 ^ (row & 7))] = W4g[f];
    }
    __syncthreads();

    const float* gate = ws + OFF_GATE;
    const float* y    = ws + OFF_Y;
    const float lw = ln_w[d], lb = ln_b[d];

#pragma unroll
    for (int it = 0; it < 4; ++it) {
        const int tok = blockIdx.x*16 + it*4 + wv;
        const float yt = y[tok];
        const float g0 = gate[tok*DI + d];
        const float g1 = gate[tok*DI + 64 + d];
        vbuf[wv][d]      = yt * (g0 / (1.f + __expf(-g0)));   // wave-private
        vbuf[wv][64 + d] = yt * (g1 / (1.f + __expf(-g1)));

        float ac0 = 0.f, ac1 = 0.f, ac2 = 0.f, ac3 = 0.f;
#pragma unroll 8
        for (int q = 0; q < 32; ++q) {
            const float4 w  = Wl[d*32 + (q ^ (d & 7))];       // spread banks
            const float4 vv = *(const float4*)(&vbuf[wv][q*4]); // broadcast
            ac0 = fmaf(w.x, vv.x, ac0);
            ac1 = fmaf(w.y, vv.y, ac1);
            ac2 = fmaf(w.z, vv.z, ac2);
            ac3 = fmaf(w.w, vv.w, ac3);
        }
        const float z  = (ac0+ac1) + (ac2+ac3) + x[tok*DM + d];
        const float s1 = wave64_sum(z);
        const float s2 = wave64_sum(z*z);
        const float mu  = s1 * (1.f/64.f);
        const float var = s2 * (1.f/64.f) - mu*mu;
        out[tok*DM + d] = (z - mu) * rsqrtf(var + 1e-5f) * lw + lb;
    }
}

extern "C" void kernel_launch(void* const* d_in, const int* in_sizes, int n_in,
                              void* d_out, int out_size, void* d_ws, size_t ws_size,
                              hipStream_t stream) {
    const float* x       = (const float*)d_in[0];
    const float* W_in    = (const float*)d_in[1];
    const float* W_delta = (const float*)d_in[2];
    const float* b_delta = (const float*)d_in[3];
    const float* W_B     = (const float*)d_in[4];
    const float* b_B     = (const float*)d_in[5];
    const float* W_C     = (const float*)d_in[6];
    const float* b_C     = (const float*)d_in[7];
    const float* A       = (const float*)d_in[8];
    const float* W_out   = (const float*)d_in[9];
    const float* ln_w    = (const float*)d_in[10];
    const float* ln_b    = (const float*)d_in[11];
    float* out = (float*)d_out;
    float* ws  = (float*)d_ws;

    hipLaunchKernelGGL(k_proj,  dim3(4*PROJ_TG), dim3(256), 0, stream,
                       x, W_in, W_delta, b_delta, W_B, b_B, W_C, b_C, ws);
    hipLaunchKernelGGL(k_abar,  dim3(512),  dim3(256), 0, stream, A, ws);
    hipLaunchKernelGGL(k_scan1, dim3(256),  dim3(128), 0, stream, ws);
    hipLaunchKernelGGL(k_scan2, dim3(256),  dim3(128), 0, stream, ws);
    hipLaunchKernelGGL(k_out,   dim3(256),  dim3(256), 0, stream,
                       x, W_out, ln_w, ln_b, ws, out);
}

// Round 4
// 53.262 us; speedup vs baseline: 1.9185x; 1.0242x over previous
//
#include <hip/hip_runtime.h>
#include <math.h>

#define NB   4
#define SL   1024
#define NTOK (NB*SL)      // 4096
#define DM   64           // d_model
#define DI   128          // d_inner
#define DSt  128          // d_state
#define SEGLEN 16
#define NSEG (SL/SEGLEN)  // 64

// ---- workspace layout (float offsets) ----
#define OFF_GATE   0
#define OFF_DELTA  (OFF_GATE  + NTOK*DI)     // softplus(delta); dead after k_abar
#define OFF_BM     (OFF_DELTA + NTOK*DI)
#define OFF_CM     (OFF_BM    + NTOK*DSt)
#define OFF_XPOOL  (OFF_CM    + NTOK*DSt)
#define OFF_ABAR   (OFF_XPOOL + NTOK)
// aliases into the dead DELTA region (written by k_scan1, after k_abar is done)
#define OFF_HEND   (OFF_DELTA)                       // NB*NSEG*DSt = 32768
#define OFF_P      (OFF_DELTA + NB*NSEG*DSt)         // 32768

#define PROJ_TOK 32
#define PROJ_TG  (NTOK/PROJ_TOK)   // 128 token groups

static __device__ __forceinline__ float wave64_sum(float v) {
#pragma unroll
    for (int m = 32; m >= 1; m >>= 1) v += __shfl_xor(v, m, 64);
    return v;
}

// ---- K1: projections. grid = 4 cats x 128 token-groups.
// All global traffic coalesced: x tile -> LDS, W panel -> LDS (then swizzled
// ds_read_b128 into per-lane VGPRs). Lane l owns rows l, l+64; stores coalesced.
__global__ __launch_bounds__(256) void k_proj(
    const float* __restrict__ x, const float* __restrict__ W_in,
    const float* __restrict__ W_delta, const float* __restrict__ b_delta,
    const float* __restrict__ W_B, const float* __restrict__ b_B,
    const float* __restrict__ W_C, const float* __restrict__ b_C,
    float* __restrict__ ws)
{
    __shared__ float  xl[PROJ_TOK*DM];   // 8 KB
    __shared__ float4 Wl[DI*16];         // 32 KB, [row][k ^ (row&15)]
    const int tid = threadIdx.x;
    const int l   = tid & 63;
    const int w   = tid >> 6;
    const int cat = blockIdx.x >> 7;     // 0 gate, 1 delta, 2 B, 3 C
    const int tg  = blockIdx.x & (PROJ_TG-1);
    const int tok0 = tg * PROJ_TOK;

    const float* Wbase; const float* bias; float* dst;
    if      (cat == 0) { Wbase = W_in + DI*DM; bias = nullptr; dst = ws + OFF_GATE;  }
    else if (cat == 1) { Wbase = W_delta;      bias = b_delta; dst = ws + OFF_DELTA; }
    else if (cat == 2) { Wbase = W_B;          bias = b_B;     dst = ws + OFF_BM;    }
    else               { Wbase = W_C;          bias = b_C;     dst = ws + OFF_CM;    }

    // stage x tile (512 f4) and weight panel (2048 f4), both fully coalesced
    {
        const float4* xg = (const float4*)(x + tok0*DM);
        float4* xl4 = (float4*)xl;
        xl4[tid]       = xg[tid];
        xl4[tid + 256] = xg[tid + 256];
        const float4* Wg = (const float4*)Wbase;
#pragma unroll
        for (int j = 0; j < 8; ++j) {
            const int f = tid + j*256;          // float4 index 0..2047
            const int row = f >> 4, k = f & 15;
            Wl[row*16 + (k ^ (row & 15))] = Wg[f];
        }
    }
    __syncthreads();

    // per-lane weight rows l and l+64 -> VGPRs via swizzled (2-way max) reads
    float4 w0[16], w1[16];
#pragma unroll
    for (int k = 0; k < 16; ++k) {
        w0[k] = Wl[l*16      + (k ^ (l & 15))];
        w1[k] = Wl[(l+64)*16 + (k ^ (l & 15))];
    }
    float bias0 = 0.f, bias1 = 0.f;
    if (bias) { bias0 = bias[l]; bias1 = bias[l+64]; }

#pragma unroll 2
    for (int it = 0; it < PROJ_TOK/4; ++it) {
        const int tl = it*4 + w;        // wave-uniform local token
        float a0=0.f,a1=0.f,a2=0.f,a3=0.f, c0=0.f,c1=0.f,c2=0.f,c3=0.f;
#pragma unroll
        for (int k = 0; k < 16; ++k) {
            const float4 xv = *(const float4*)(xl + tl*DM + 4*k);  // broadcast
            a0 = fmaf(w0[k].x, xv.x, a0);
            a1 = fmaf(w0[k].y, xv.y, a1);
            a2 = fmaf(w0[k].z, xv.z, a2);
            a3 = fmaf(w0[k].w, xv.w, a3);
            c0 = fmaf(w1[k].x, xv.x, c0);
            c1 = fmaf(w1[k].y, xv.y, c1);
            c2 = fmaf(w1[k].z, xv.z, c2);
            c3 = fmaf(w1[k].w, xv.w, c3);
        }
        float ra = (a0+a1) + (a2+a3) + bias0;
        float rb = (c0+c1) + (c2+c3) + bias1;
        if (cat == 1) {  // softplus, numerically stable
            ra = fmaxf(ra, 0.f) + log1pf(__expf(-fabsf(ra)));
            rb = fmaxf(rb, 0.f) + log1pf(__expf(-fabsf(rb)));
        }
        const int tok = tok0 + tl;
        dst[tok*128 + l]      = ra;   // coalesced 256B
        dst[tok*128 + 64 + l] = rb;   // coalesced 256B
    }

    if (cat == 0) {   // x_pool = x . w_pool (mean over x_ssm dims folded into W)
        float wp = 0.f;
#pragma unroll 8
        for (int i = 0; i < DI; ++i) wp += W_in[i*DM + l];   // coalesced
        wp *= (1.0f/DI);
#pragma unroll
        for (int it = 0; it < PROJ_TOK/4; ++it) {
            const int tl = it*4 + w;
            float v = xl[tl*DM + l] * wp;   // stride-1: conflict-free
            v = wave64_sum(v);
            if (l == 0) ws[OFF_XPOOL + tok0 + tl] = v;
        }
    }
}

// ---- K2: Abar[t,s] = mean_i exp(delta[t,i] * A[i,s]); A column in VGPRs ----
__global__ __launch_bounds__(256, 2) void k_abar(const float* __restrict__ A,
                                                 float* __restrict__ ws)
{
    const int tid  = threadIdx.x;
    const int s    = tid & 127;
    const int half = tid >> 7;
    float areg[DI];
#pragma unroll
    for (int i = 0; i < DI; ++i) areg[i] = A[i*DSt + s];   // coalesced, L2-hot

    const float* delta = ws + OFF_DELTA;
    float*       Abar  = ws + OFF_ABAR;
    const int base = blockIdx.x * 8 + half * 4;
#pragma unroll
    for (int p = 0; p < 4; ++p) {
        const int tok = base + p;
        const float* dv = delta + tok*DI;
        float a0 = 0.f, a1 = 0.f, a2 = 0.f, a3 = 0.f;
#pragma unroll
        for (int i4 = 0; i4 < DI/4; ++i4) {
            const float4 d4 = *(const float4*)(dv + 4*i4);  // wave-uniform bcast
            a0 += __expf(d4.x * areg[4*i4    ]);
            a1 += __expf(d4.y * areg[4*i4 + 1]);
            a2 += __expf(d4.z * areg[4*i4 + 2]);
            a3 += __expf(d4.w * areg[4*i4 + 3]);
        }
        Abar[tok*DSt + s] = ((a0+a1) + (a2+a3)) * (1.0f/DI);
    }
}

// ---- K3: scan pass 1 — per-segment local scan (h0=0) ----
__global__ __launch_bounds__(128) void k_scan1(float* __restrict__ ws)
{
    const int s   = threadIdx.x;
    const int b   = blockIdx.x >> 6;
    const int seg = blockIdx.x & 63;
    const float* Abar  = ws + OFF_ABAR;
    const float* Bm    = ws + OFF_BM;
    const float* xpool = ws + OFF_XPOOL;
    float h = 0.f, p = 1.f;
    const int t0 = b*SL + seg*SEGLEN;
#pragma unroll
    for (int t = 0; t < SEGLEN; ++t) {
        const float a  = Abar[(t0 + t)*DSt + s];
        const float bx = Bm[(t0 + t)*DSt + s] * xpool[t0 + t];
        h = fmaf(a, h, bx);
        p *= a;
    }
    ws[OFF_HEND + blockIdx.x*DSt + s] = h;
    ws[OFF_P    + blockIdx.x*DSt + s] = p;
}

// ---- K4: fused scan pass 2 + output. Block = 256 threads = 2 segments
// (32 tokens). Phase A: prefix stitch + local re-scan + y reduce (y in LDS).
// Phase B: y*silu(gate) @ W_out^T + residual + LayerNorm, wave per token. ----
__global__ __launch_bounds__(256) void k_scan2_out(
    const float* __restrict__ x, const float* __restrict__ W_out,
    const float* __restrict__ ln_w, const float* __restrict__ ln_b,
    float* __restrict__ ws, float* __restrict__ out)
{
    __shared__ float  prod[2*SEGLEN][132];
    __shared__ float4 Wl[DM*32];          // [row][c4 ^ (row&7)]
    __shared__ float  vbuf[4][DI];
    __shared__ float  y_lds[2*SEGLEN];

    const int tid   = threadIdx.x;
    const int lane  = tid & 63;
    const int w     = tid >> 6;
    const int shalf = tid & 127;          // state index within segment
    const int wp    = tid >> 7;           // which of 2 segments
    const int b     = blockIdx.x >> 5;
    const int sg    = blockIdx.x & 31;
    const int seg   = sg*2 + wp;

    // stage W_out (2048 f4, coalesced -> swizzled)
    const float4* W4g = (const float4*)W_out;
#pragma unroll
    for (int j = 0; j < 8; ++j) {
        const int f = tid + j*256;
        const int row = f >> 5, c4 = f & 31;
        Wl[row*32 + (c4 ^ (row & 7))] = W4g[f];
    }

    const float* Abar  = ws + OFF_ABAR;
    const float* Bm    = ws + OFF_BM;
    const float* Cm    = ws + OFF_CM;
    const float* xpool = ws + OFF_XPOOL;
    const float* hend  = ws + OFF_HEND;
    const float* P     = ws + OFF_P;

    // phase A: prefix stitch (wave-uniform trip count)
    float h = 0.f;
#pragma unroll 4
    for (int j = 0; j < seg; ++j) {
        const int idx = (b*NSEG + j)*DSt + shalf;
        h = fmaf(P[idx], h, hend[idx]);
    }
    const int t0 = b*SL + seg*SEGLEN;
#pragma unroll
    for (int t = 0; t < SEGLEN; ++t) {
        const float a  = Abar[(t0 + t)*DSt + shalf];
        const float bx = Bm[(t0 + t)*DSt + shalf] * xpool[t0 + t];
        h = fmaf(a, h, bx);
        prod[wp*SEGLEN + t][shalf] = Cm[(t0 + t)*DSt + shalf] * h;
    }
    __syncthreads();

    // y reduce: 8 lanes per token
    {
        const int t = shalf >> 3, r = lane & 7;
        const int row = wp*SEGLEN + t;
        float4 acc4 = {0.f,0.f,0.f,0.f};
#pragma unroll
        for (int k4 = 0; k4 < 4; ++k4) {
            const float4 v = *(const float4*)(&prod[row][r*16 + 4*k4]);
            acc4.x += v.x; acc4.y += v.y; acc4.z += v.z; acc4.w += v.w;
        }
        float acc = (acc4.x + acc4.y) + (acc4.z + acc4.w);
#pragma unroll
        for (int m = 1; m <= 4; m <<= 1) acc += __shfl_xor(acc, m, 64);
        if (r == 0) y_lds[row] = acc;
    }
    __syncthreads();

    // phase B: 8 tokens per wave
    const float* gate = ws + OFF_GATE;
    const int d = lane;
    const float lw = ln_w[d], lb = ln_b[d];
#pragma unroll 2
    for (int j = 0; j < 8; ++j) {
        const int tloc = w*8 + j;
        const int tok  = b*SL + sg*32 + tloc;
        const float yt = y_lds[tloc];
        const float g0 = gate[tok*DI + d];
        const float g1 = gate[tok*DI + 64 + d];
        vbuf[w][d]      = yt * (g0 / (1.f + __expf(-g0)));   // wave-private
        vbuf[w][64 + d] = yt * (g1 / (1.f + __expf(-g1)));

        float ac0 = 0.f, ac1 = 0.f, ac2 = 0.f, ac3 = 0.f;
#pragma unroll 8
        for (int q = 0; q < 32; ++q) {
            const float4 wv = Wl[d*32 + (q ^ (d & 7))];        // spread banks
            const float4 vv = *(const float4*)(&vbuf[w][q*4]); // broadcast
            ac0 = fmaf(wv.x, vv.x, ac0);
            ac1 = fmaf(wv.y, vv.y, ac1);
            ac2 = fmaf(wv.z, vv.z, ac2);
            ac3 = fmaf(wv.w, vv.w, ac3);
        }
        const float z  = (ac0+ac1) + (ac2+ac3) + x[tok*DM + d];
        const float s1 = wave64_sum(z);
        const float s2 = wave64_sum(z*z);
        const float mu  = s1 * (1.f/64.f);
        const float var = s2 * (1.f/64.f) - mu*mu;
        out[tok*DM + d] = (z - mu) * rsqrtf(var + 1e-5f) * lw + lb;
    }
}

extern "C" void kernel_launch(void* const* d_in, const int* in_sizes, int n_in,
                              void* d_out, int out_size, void* d_ws, size_t ws_size,
                              hipStream_t stream) {
    const float* x       = (const float*)d_in[0];
    const float* W_in    = (const float*)d_in[1];
    const float* W_delta = (const float*)d_in[2];
    const float* b_delta = (const float*)d_in[3];
    const float* W_B     = (const float*)d_in[4];
    const float* b_B     = (const float*)d_in[5];
    const float* W_C     = (const float*)d_in[6];
    const float* b_C     = (const float*)d_in[7];
    const float* A       = (const float*)d_in[8];
    const float* W_out   = (const float*)d_in[9];
    const float* ln_w    = (const float*)d_in[10];
    const float* ln_b    = (const float*)d_in[11];
    float* out = (float*)d_out;
    float* ws  = (float*)d_ws;

    hipLaunchKernelGGL(k_proj,      dim3(4*PROJ_TG), dim3(256), 0, stream,
                       x, W_in, W_delta, b_delta, W_B, b_B, W_C, b_C, ws);
    hipLaunchKernelGGL(k_abar,      dim3(512),  dim3(256), 0, stream, A, ws);
    hipLaunchKernelGGL(k_scan1,     dim3(256),  dim3(128), 0, stream, ws);
    hipLaunchKernelGGL(k_scan2_out, dim3(128),  dim3(256), 0, stream,
                       x, W_out, ln_w, ln_b, ws, out);
}